// Round 6
// baseline (38.722 us; speedup 1.0000x reference)
//
#include <hip/hip_runtime.h>

#define BATCH  8
#define NPTS   4096
#define TPB    256
#define QPT    4                    // queries per thread
#define QPB    (TPB * QPT)          // 1024 queries per block
#define QTILES (NPTS / QPB)         // 4 query tiles per batch
#define NSEG   32
#define SEG    (NPTS / NSEG)        // 128 ref points per block
#define SPAIR  (SEG / 2)            // 64 ref pairs per block
#define NPAIRS (NPTS / 2)           // 2048 ref pairs per batch cloud
#define HCLOUD (BATCH * NPAIRS)     // 16384 pairs per cloud
#define CLOUD  (BATCH * NPTS)       // 32768 points per cloud
#define QTOTAL (2 * CLOUD)          // 65536 outputs

typedef float v2f __attribute__((ext_vector_type(2)));
typedef float v4f __attribute__((ext_vector_type(4)));

// Packed fp32 fma with the ref coords coming straight from SGPRs (VOP3P
// allows one scalar source). Query (b) and accumulator (c) are VGPRs.
__device__ inline v2f pk_fma_svv(v2f a_sgpr, v2f b, v2f c) {
    v2f d;
    asm("v_pk_fma_f32 %0, %1, %2, %3" : "=v"(d) : "s"(a_sgpr), "v"(b), "v"(c));
    return d;
}
__device__ inline float fmin3(float a, float b, float c) {
    float d;
    asm("v_min3_f32 %0, %1, %2, %3" : "=v"(d) : "v"(a), "v"(b), "v"(c));
    return d;
}

// ws layout: [pre: 32768 pairs * 32 B = 1 MB][part: 16 dirb * 32 seg * 4096 * 4 B = 8 MB]
#define PART_OFF_FLOATS (2 * HCLOUD * 2 * 4)

// One thread per ref PAIR: pair-transposed preprocessed layout
//   pre[2p]   = (-2x0, -2x1, -2y0, -2y1)
//   pre[2p+1] = (-2z0, -2z1,  w0,   w1)   w = x^2+y^2+z^2
__global__ __launch_bounds__(TPB) void nnd_prep(const float* __restrict__ xyz1,
                                                const float* __restrict__ xyz2,
                                                v4f* __restrict__ pre) {
    int i = blockIdx.x * TPB + (int)threadIdx.x;       // 0..32767 (pair id)
    const float* src = (i < HCLOUD) ? xyz1 : xyz2;
    int j = (i < HCLOUD) ? i : i - HCLOUD;
    const float* p = src + (size_t)j * 6;
    float x0 = p[0], y0 = p[1], z0 = p[2];
    float x1 = p[3], y1 = p[4], z1 = p[5];
    float w0 = x0 * x0 + y0 * y0 + z0 * z0;
    float w1 = x1 * x1 + y1 * y1 + z1 * z1;
    pre[2 * i + 0] = (v4f){-2.f * x0, -2.f * x1, -2.f * y0, -2.f * y1};
    pre[2 * i + 1] = (v4f){-2.f * z0, -2.f * z1, w0, w1};
}

// Main: block = (dir, batch, qtile, segment). Ref pairs arrive via uniform
// s_loads and FEED THE PACKED FMA DIRECTLY FROM SGPRs (1 scalar src/inst is
// legal); only w01 is materialized to VGPR once per pair. Per ref-pair:
// 2 v_mov + 12 v_pk_fma_f32 + 4 v_min3 = 18 VALU for 8 distances.
__global__ __launch_bounds__(TPB, 8) void nnd_main(const float* __restrict__ xyz1,
                                                   const float* __restrict__ xyz2,
                                                   const v4f* __restrict__ pre,
                                                   float* __restrict__ part) {
    const int bid  = blockIdx.x;                 // 2048 blocks
    const int seg  = bid & (NSEG - 1);           // 5 bits
    const int tile = (bid >> 5) & (QTILES - 1);  // 2 bits
    const int b    = (bid >> 7) & (BATCH - 1);   // 3 bits
    const int dir  = bid >> 10;                  // 1 bit

    const float* q  = (dir == 0) ? xyz1 : xyz2;
    const v4f*   rp = pre + 2 * ((size_t)(dir == 0 ? 1 : 0) * HCLOUD
                                 + (size_t)b * NPAIRS + (size_t)seg * SPAIR);

    // 4 consecutive queries per thread: 12 floats = 3 aligned float4 loads.
    const int n0 = tile * QPB + (int)threadIdx.x * QPT;
    const float4* qv = (const float4*)(q + ((size_t)b * NPTS + n0) * 3);
    float4 fa = qv[0], fb = qv[1], fc = qv[2];
    const float qx[QPT] = {fa.x, fa.w, fb.z, fc.y};
    const float qy[QPT] = {fa.y, fb.x, fb.w, fc.z};
    const float qz[QPT] = {fa.z, fb.y, fc.x, fc.w};

    v2f qx2[QPT], qy2[QPT], qz2[QPT];
    #pragma unroll
    for (int k = 0; k < QPT; ++k) {
        qx2[k] = (v2f){qx[k], qx[k]};
        qy2[k] = (v2f){qy[k], qy[k]};
        qz2[k] = (v2f){qz[k], qz[k]};
    }

    float best[QPT] = {1e30f, 1e30f, 1e30f, 1e30f};

    #pragma unroll 8
    for (int p = 0; p < SPAIR; ++p) {
        v4f A  = rp[2 * p];                       // uniform -> s_load
        v4f Bv = rp[2 * p + 1];
        v2f x01 = __builtin_shufflevector(A, A, 0, 1);    // stays in SGPRs
        v2f y01 = __builtin_shufflevector(A, A, 2, 3);
        v2f z01 = __builtin_shufflevector(Bv, Bv, 0, 1);
        v2f w01 = __builtin_shufflevector(Bv, Bv, 2, 3);  // -> VGPR once ("v" use)
        #pragma unroll
        for (int k = 0; k < QPT; ++k) {
            v2f e = pk_fma_svv(x01, qx2[k], w01);  // w01: the one v-materialization
            e = pk_fma_svv(y01, qy2[k], e);
            e = pk_fma_svv(z01, qz2[k], e);
            best[k] = fmin3(best[k], e.x, e.y);
        }
    }

    // part[(dir*BATCH+b)][seg][n0..n0+3] — one aligned float4 store.
    float* dst = part + ((size_t)(dir * BATCH + b) * NSEG + seg) * NPTS + n0;
    float4 r;
    r.x = best[0] + (qx[0] * qx[0] + qy[0] * qy[0] + qz[0] * qz[0]);
    r.y = best[1] + (qx[1] * qx[1] + qy[1] * qy[1] + qz[1] * qz[1]);
    r.z = best[2] + (qx[2] * qx[2] + qy[2] * qy[2] + qz[2] * qz[2]);
    r.w = best[3] + (qx[3] * qx[3] + qy[3] * qy[3] + qz[3] * qz[3]);
    *(float4*)dst = r;
}

// Fold the NSEG partials per query.
__global__ __launch_bounds__(TPB) void nnd_reduce(const float* __restrict__ part,
                                                  float* __restrict__ out) {
    int qid = blockIdx.x * TPB + (int)threadIdx.x;    // 0..65535
    int db = qid >> 12;                               // dir*BATCH+b
    int n  = qid & (NPTS - 1);
    const float* p = part + (size_t)db * NSEG * NPTS + n;
    float m = p[0];
    #pragma unroll
    for (int sgm = 1; sgm < NSEG; ++sgm) m = fminf(m, p[(size_t)sgm * NPTS]);
    out[qid] = m;
}

extern "C" void kernel_launch(void* const* d_in, const int* in_sizes, int n_in,
                              void* d_out, int out_size, void* d_ws, size_t ws_size,
                              hipStream_t stream) {
    const float* xyz1 = (const float*)d_in[0];
    const float* xyz2 = (const float*)d_in[1];
    v4f*   pre  = (v4f*)d_ws;
    float* part = (float*)d_ws + PART_OFF_FLOATS;
    float* out  = (float*)d_out;

    nnd_prep<<<(2 * HCLOUD) / TPB, TPB, 0, stream>>>(xyz1, xyz2, pre);
    nnd_main<<<2 * BATCH * QTILES * NSEG, TPB, 0, stream>>>(xyz1, xyz2, pre, part);
    nnd_reduce<<<QTOTAL / TPB, TPB, 0, stream>>>(part, out);
}